// Round 15
// baseline (574.274 us; speedup 1.0000x reference)
//
#include <hip/hip_runtime.h>
#include <stdint.h>

#define M_DIM 8192
#define K_DIM 4096
#define N_DIM 12288

typedef int v4i __attribute__((ext_vector_type(4)));

#define GLDS16(g, l)                                                         \
  __builtin_amdgcn_global_load_lds(                                          \
      (const __attribute__((address_space(1))) void*)(g),                    \
      (__attribute__((address_space(3))) void*)(l), 16, 0, 0)

#define BARRIER() asm volatile("s_barrier" ::: "memory")
#define VMCNT0() asm volatile("s_waitcnt vmcnt(0)" ::: "memory")

// ---------------------------------------------------------------------------
// Fused prep: blocks [0, M) quantize x rows; blocks [M, M+12288) pack weights
// row-major int8 (proven path, unchanged).
// ---------------------------------------------------------------------------
__global__ __launch_bounds__(256) void prep(const float* __restrict__ x,
                                            int8_t* __restrict__ xq,
                                            float* __restrict__ xs,
                                            const int* __restrict__ w32,
                                            int8_t* __restrict__ w8) {
  const int t = threadIdx.x;
  if ((int)blockIdx.x < M_DIM) {
    const int row = blockIdx.x;
    const float* xr = x + (size_t)row * K_DIM;

    float4 v[4];
    float amax = 0.f;
#pragma unroll
    for (int i = 0; i < 4; ++i) {
      v[i] = reinterpret_cast<const float4*>(xr)[t * 4 + i];
      amax = fmaxf(amax, fmaxf(fmaxf(fabsf(v[i].x), fabsf(v[i].y)),
                               fmaxf(fabsf(v[i].z), fabsf(v[i].w))));
    }
#pragma unroll
    for (int off = 32; off > 0; off >>= 1)
      amax = fmaxf(amax, __shfl_xor(amax, off));

    __shared__ float smax[4];
    if ((t & 63) == 0) smax[t >> 6] = amax;
    __syncthreads();
    amax = fmaxf(fmaxf(smax[0], smax[1]), fmaxf(smax[2], smax[3]));

    const float scale = fmaxf(amax, 1e-8f) / 127.f;

    union {
      int8_t b[16];
      v4i v;
    } p;
    const float* pv = reinterpret_cast<const float*>(v);
#pragma unroll
    for (int i = 0; i < 16; ++i) {
      float r = rintf(pv[i] / scale);  // round-half-to-even == jnp.round
      r = fminf(127.f, fmaxf(-127.f, r));
      p.b[i] = (int8_t)(int)r;
    }
    reinterpret_cast<v4i*>(xq + (size_t)row * K_DIM)[t] = p.v;
    if (t == 0) xs[row] = scale;
  } else {
    const size_t i = (((size_t)blockIdx.x - M_DIM) * 256 + t) * 16;
    const int4* src = reinterpret_cast<const int4*>(w32 + i);
    union {
      int8_t b[16];
      v4i v;
    } p;
#pragma unroll
    for (int c = 0; c < 4; ++c) {
      int4 q = src[c];
      p.b[c * 4 + 0] = (int8_t)q.x;
      p.b[c * 4 + 1] = (int8_t)q.y;
      p.b[c * 4 + 2] = (int8_t)q.z;
      p.b[c * 4 + 3] = (int8_t)q.w;
    }
    *reinterpret_cast<v4i*>(w8 + i) = p.v;
  }
}

// ---------------------------------------------------------------------------
// int8 GEMM r15: 256x256 tile, 4 waves (2x2 grid, 128x128 PER WAVE), BK=128B.
// r14 lesson: 128^2 tiles double LDS-pipe load per matrix-cycle -> worse.
// This round cuts LDS reads per MFMA instead: per-wave 128x128 output needs
// 32 b128 reads per 128 MFMAs (0.25 vs r13's 0.375) -> block LDS traffic
// 131KB/tile (~2048 cyc) < matrix (~2613 cyc): LDS pipe leaves the critical
// path with no reliance on cross-wave overlap. Cost: acc 256 VGPR + 4 frag
// sets (~410 total) -> 1 wave/SIMD (m08: no spill through 450).
// All proven mechanics unchanged: one vmcnt(0)+barrier per K-tile, XOR
// swizzle (inverse on global source), base+imm ds_read_b128, XCD windows.
// ---------------------------------------------------------------------------
#define BM 256
#define BN 256
#define BKB 128                 // K bytes per tile
#define NTILES (K_DIM / BKB)    // 32

__global__ __launch_bounds__(256, 1) void gemm_i8(
    const int8_t* __restrict__ xq, const float* __restrict__ xs,
    const int8_t* __restrict__ w8, const float* __restrict__ wsc,
    const float* __restrict__ bias, float* __restrict__ out) {
  // LDS map: A bufs at c*32768 (256 rows x 128B), B bufs at 65536 + c*32768.
  __shared__ __align__(16) int8_t lds[131072];

  const int t = threadIdx.x;
  const int lane = t & 63;
  const int w = t >> 6;      // wave 0..3
  const int wr = w >> 1;     // 0..1 -> 128-row block
  const int wc = w & 1;      // 0..1 -> 128-col block
  const int fr = lane & 15;
  const int kq = lane >> 4;  // 0..3
  const int l7 = lane & 7;

  // 2D XCD swizzle: XCD x owns M-tiles [4x,4x+4); 4M x 8N windows
  // (bijective: 8 xcd * 6 g * 32 j = 1536).
  const int bid = (int)blockIdx.x;
  const int xcd = bid & 7;
  const int q = bid >> 3;    // [0,192)
  const int g = q >> 5;      // [0,6)
  const int j = q & 31;
  const int rowBase = (xcd * 4 + (j >> 3)) * BM;
  const int colBase = (g * 8 + (j & 7)) * BN;

  // staging: thread t -> row srow = t>>3 (0..31), lds 16B-slot t&7; inverse
  // swizzle on the GLOBAL source so lds(R,S) holds global chunk S ^ (R&7).
  // 256 threads x 16B = 4KB = 32-row slab per stage call.
  const int srow = t >> 3;
  const int gslot = (t & 7) ^ (srow & 7);
  const int8_t* gA = xq + (size_t)(rowBase + srow) * K_DIM + gslot * 16;
  const int8_t* gB = w8 + (size_t)(colBase + srow) * K_DIM + gslot * 16;
  int8_t* ldsw = lds + w * 1024;  // wave-uniform dest base (HW adds lane*16)

#define STAGE_A(c, r0, k0) \
  GLDS16(gA + (size_t)(r0) * K_DIM + (k0), ldsw + (c) * 32768 + (r0) * 128)
#define STAGE_B(c, r0, k0) \
  GLDS16(gB + (size_t)(r0) * K_DIM + (k0), ldsw + 65536 + (c) * 32768 + (r0) * 128)

#define STAGE16(d, k1)                                                        \
  STAGE_B(d, 0, k1); STAGE_B(d, 32, k1);                                      \
  STAGE_B(d, 64, k1); STAGE_B(d, 96, k1);                                     \
  STAGE_B(d, 128, k1); STAGE_B(d, 160, k1);                                   \
  STAGE_B(d, 192, k1); STAGE_B(d, 224, k1);                                   \
  STAGE_A(d, 0, k1); STAGE_A(d, 32, k1);                                      \
  STAGE_A(d, 64, k1); STAGE_A(d, 96, k1);                                     \
  STAGE_A(d, 128, k1); STAGE_A(d, 160, k1);                                   \
  STAGE_A(d, 192, k1); STAGE_A(d, 224, k1);

  // fragment read slot: (ks*4 + kq) ^ (row&7); row&7 == l7 (bases mult-16).
  const int s0_ = kq ^ l7;        // ks=0
  const int s1_ = s0_ ^ 4;        // ks=1
  const int rA = wr * 128 + fr;   // + mi*16, mi 0..7
  const int rB = wc * 128 + fr;   // + ni*16, ni 0..7

  // Precomputed per-thread LDS base pointers; every fragment read is a single
  // ds_read_b128 with a 16-bit immediate (max byte imm 65520 < 65536).
  const v4i* pA0 = (const v4i*)lds + ((rA << 3) + s0_);
  const v4i* pA1 = (const v4i*)lds + ((rA << 3) + s1_);
  const v4i* pB0 = (const v4i*)(lds + 65536) + ((rB << 3) + s0_);
  const v4i* pB1 = (const v4i*)(lds + 65536) + ((rB << 3) + s1_);

#define LDA8(dst, c, ks)                                                      \
  {                                                                           \
    const v4i* _p = (ks) ? pA1 : pA0;                                         \
    _Pragma("unroll") for (int mi = 0; mi < 8; ++mi)                          \
        dst[mi] = _p[((c) << 11) + (mi << 7)];                                \
  }
#define LDB8(dst, c, ks)                                                      \
  {                                                                           \
    const v4i* _p = (ks) ? pB1 : pB0;                                         \
    _Pragma("unroll") for (int ni = 0; ni < 8; ++ni)                          \
        dst[ni] = _p[((c) << 11) + (ni << 7)];                                \
  }

#define MFMA64(A_, B_)                                                        \
  __builtin_amdgcn_s_setprio(1);                                              \
  _Pragma("unroll") for (int ni = 0; ni < 8; ++ni)                            \
      _Pragma("unroll") for (int mi = 0; mi < 8; ++mi)                        \
          acc[mi][ni] = __builtin_amdgcn_mfma_i32_16x16x64_i8(                \
              A_[mi], B_[ni], acc[mi][ni], 0, 0, 0);                          \
  __builtin_amdgcn_s_setprio(0);

  v4i acc[8][8];
#pragma unroll
  for (int i = 0; i < 8; ++i)
#pragma unroll
    for (int jj = 0; jj < 8; ++jj) acc[i][jj] = (v4i){0, 0, 0, 0};

  v4i a0[8], a1[8], b0[8], b1[8];

  // One K-tile: stage next tile (16 GLDS), issue ks=1 fragment reads into the
  // second register set, two 64-MFMA blocks, single vmcnt(0)+barrier, then
  // prefetch next tile's ks=0 fragments.
#define TILE(c, d, k1)                                                        \
  STAGE16(d, k1);                                                             \
  LDA8(a1, c, 1);                                                             \
  LDB8(b1, c, 1);                                                             \
  MFMA64(a0, b0);                                                             \
  MFMA64(a1, b1);                                                             \
  VMCNT0();                                                                   \
  BARRIER();                                                                  \
  LDA8(a0, d, 0);                                                             \
  LDB8(b0, d, 0);

#define TILE_LAST(c)                                                          \
  LDA8(a1, c, 1);                                                             \
  LDB8(b1, c, 1);                                                             \
  MFMA64(a0, b0);                                                             \
  MFMA64(a1, b1);

  // prologue: tile0 -> buf0; drain; load tile0's ks=0 fragment sets.
  STAGE16(0, 0);
  VMCNT0();
  BARRIER();
  LDA8(a0, 0, 0);
  LDB8(b0, 0, 0);

  for (int tt = 0; tt < NTILES - 2; tt += 2) {  // tiles 0..29
    TILE(0, 1, (tt + 1) * BKB);
    TILE(1, 0, (tt + 2) * BKB);
  }
  TILE(0, 1, (NTILES - 1) * BKB);  // tile 30, stages tile 31
  TILE_LAST(1);                    // tile 31

  // epilogue: C/D layout col = lane&15, row = (lane>>4)*4 + reg
  const int orow0 = rowBase + wr * 128;
  const int ocol0 = colBase + wc * 128;
  const int rsub = kq * 4;
#pragma unroll
  for (int mi = 0; mi < 8; ++mi) {
    const int r0 = orow0 + mi * 16 + rsub;  // multiple of 4 -> float4 load
    const float4 s4v = *reinterpret_cast<const float4*>(xs + r0);
    const float s4[4] = {s4v.x, s4v.y, s4v.z, s4v.w};
#pragma unroll
    for (int ni = 0; ni < 8; ++ni) {
      const int col = ocol0 + ni * 16 + fr;
      const float wf = wsc[col];
      const float bb = bias[col];
#pragma unroll
      for (int r = 0; r < 4; ++r)
        out[(size_t)(r0 + r) * N_DIM + col] =
            (float)acc[mi][ni][r] * s4[r] * wf + bb;
    }
  }
}

// ---------------------------------------------------------------------------
extern "C" void kernel_launch(void* const* d_in, const int* in_sizes, int n_in,
                              void* d_out, int out_size, void* d_ws,
                              size_t ws_size, hipStream_t stream) {
  const float* x = (const float*)d_in[0];
  const int* w32 = (const int*)d_in[1];
  const float* wscale = (const float*)d_in[2];
  const float* bias = (const float*)d_in[3];
  float* out = (float*)d_out;

  int8_t* xq = (int8_t*)d_ws;
  float* xs = (float*)((char*)d_ws + (size_t)M_DIM * K_DIM);
  int8_t* w8 = (int8_t*)((char*)d_ws + (size_t)M_DIM * K_DIM + M_DIM * 4);

  const int packBlocks = (N_DIM * K_DIM) / (256 * 16);  // 12288
  prep<<<M_DIM + packBlocks, 256, 0, stream>>>(x, xq, xs, w32, w8);
  gemm_i8<<<(M_DIM / BM) * (N_DIM / BN), 256, 0, stream>>>(xq, xs, w8, wscale,
                                                           bias, out);
}

// Round 16
// 532.425 us; speedup vs baseline: 1.0786x; 1.0786x over previous
//
#include <hip/hip_runtime.h>
#include <stdint.h>

#define M_DIM 8192
#define K_DIM 4096
#define N_DIM 12288

typedef int v4i __attribute__((ext_vector_type(4)));

#define GLDS16(g, l)                                                         \
  __builtin_amdgcn_global_load_lds(                                          \
      (const __attribute__((address_space(1))) void*)(g),                    \
      (__attribute__((address_space(3))) void*)(l), 16, 0, 0)

#define BARRIER() asm volatile("s_barrier" ::: "memory")
#define VMCNT0() asm volatile("s_waitcnt vmcnt(0)" ::: "memory")

// ---------------------------------------------------------------------------
// Fused prep: blocks [0, M) quantize x rows; blocks [M, M+12288) pack weights
// row-major int8 (proven path, unchanged).
// ---------------------------------------------------------------------------
__global__ __launch_bounds__(256) void prep(const float* __restrict__ x,
                                            int8_t* __restrict__ xq,
                                            float* __restrict__ xs,
                                            const int* __restrict__ w32,
                                            int8_t* __restrict__ w8) {
  const int t = threadIdx.x;
  if ((int)blockIdx.x < M_DIM) {
    const int row = blockIdx.x;
    const float* xr = x + (size_t)row * K_DIM;

    float4 v[4];
    float amax = 0.f;
#pragma unroll
    for (int i = 0; i < 4; ++i) {
      v[i] = reinterpret_cast<const float4*>(xr)[t * 4 + i];
      amax = fmaxf(amax, fmaxf(fmaxf(fabsf(v[i].x), fabsf(v[i].y)),
                               fmaxf(fabsf(v[i].z), fabsf(v[i].w))));
    }
#pragma unroll
    for (int off = 32; off > 0; off >>= 1)
      amax = fmaxf(amax, __shfl_xor(amax, off));

    __shared__ float smax[4];
    if ((t & 63) == 0) smax[t >> 6] = amax;
    __syncthreads();
    amax = fmaxf(fmaxf(smax[0], smax[1]), fmaxf(smax[2], smax[3]));

    const float scale = fmaxf(amax, 1e-8f) / 127.f;

    union {
      int8_t b[16];
      v4i v;
    } p;
    const float* pv = reinterpret_cast<const float*>(v);
#pragma unroll
    for (int i = 0; i < 16; ++i) {
      float r = rintf(pv[i] / scale);  // round-half-to-even == jnp.round
      r = fminf(127.f, fmaxf(-127.f, r));
      p.b[i] = (int8_t)(int)r;
    }
    reinterpret_cast<v4i*>(xq + (size_t)row * K_DIM)[t] = p.v;
    if (t == 0) xs[row] = scale;
  } else {
    const size_t i = (((size_t)blockIdx.x - M_DIM) * 256 + t) * 16;
    const int4* src = reinterpret_cast<const int4*>(w32 + i);
    union {
      int8_t b[16];
      v4i v;
    } p;
#pragma unroll
    for (int c = 0; c < 4; ++c) {
      int4 q = src[c];
      p.b[c * 4 + 0] = (int8_t)q.x;
      p.b[c * 4 + 1] = (int8_t)q.y;
      p.b[c * 4 + 2] = (int8_t)q.z;
      p.b[c * 4 + 3] = (int8_t)q.w;
    }
    *reinterpret_cast<v4i*>(w8 + i) = p.v;
  }
}

// ---------------------------------------------------------------------------
// int8 GEMM r16: 128M x 256N tile, BK=64B, 4 waves (1x4, 128x64 per wave),
// LDS 48KB, VGPR ~190 -> TWO independent blocks per CU (8 waves/CU, 2/SIMD).
// Rationale (r13/r14/r15 post-mortems): pipes SUM under barrier lockstep;
// r14's 2-block attempt regressed only because 128^2 tiles raised LDS
// traffic per MAC. This geometry keeps reads/MAC exactly at r13's optimum
// (0.0234 B/MAC) while decorrelating two blocks so one block's stage/drain/
// barrier hides under the other's MFMA (m114 overlap).
// 64B-row swizzle: slot = kq ^ ((fr>>1)&3) -- enumerated: each 8-lane group
// covers all 32 banks exactly once; 16-lane quantum 2-way (free).
// Schedule: proven r7 one-vmcnt(0)+barrier per K-tile.
// ---------------------------------------------------------------------------
#define BM 128
#define BN 256
#define BKB 64                  // K bytes per tile
#define NTILES (K_DIM / BKB)    // 64

__global__ __launch_bounds__(256, 2) void gemm_i8(
    const int8_t* __restrict__ xq, const float* __restrict__ xs,
    const int8_t* __restrict__ w8, const float* __restrict__ wsc,
    const float* __restrict__ bias, float* __restrict__ out) {
  // LDS: A bufs at c*8192 (128 rows x 64B), B bufs at 16384 + c*16384
  // (256 rows x 64B). Total 48KB.
  __shared__ __align__(16) int8_t lds[49152];

  const int t = threadIdx.x;
  const int lane = t & 63;
  const int w = t >> 6;      // wave 0..3 -> 64-col block
  const int fr = lane & 15;
  const int kq = lane >> 4;  // 0..3 (16B k-chunk)

  // XCD swizzle: XCD x owns M-tiles [8x,8x+8); 8M x 4N windows
  // (bijective: 8 xcd * 12 g * 32 j = 3072).
  const int bid = (int)blockIdx.x;
  const int xcd = bid & 7;
  const int q = bid >> 3;    // [0,384)
  const int g = q >> 5;      // [0,12)  N-group of 4
  const int j = q & 31;      // 8M x 4N window
  const int rowBase = (xcd * 8 + (j >> 2)) * BM;
  const int colBase = (g * 4 + (j & 3)) * BN;

  // staging: thread t -> row srow = t>>2, 16B-slot t&3; inverse swizzle on
  // the GLOBAL source so lds(R,S) holds global chunk S ^ ((R>>1)&3).
  // 256 threads x 16B = 4KB = 64 rows of 64B per stage instruction.
  const int srow = t >> 2;
  const int gslot = (t & 3) ^ ((srow >> 1) & 3);
  const int8_t* gA = xq + (size_t)(rowBase + srow) * K_DIM + gslot * 16;
  const int8_t* gB = w8 + (size_t)(colBase + srow) * K_DIM + gslot * 16;
  int8_t* ldsw = lds + w * 1024;  // wave-uniform dest base (HW adds lane*16)

#define STAGE_A(c, r0, k0) \
  GLDS16(gA + (size_t)(r0) * K_DIM + (k0), ldsw + (c) * 8192 + (r0) * 64)
#define STAGE_B(c, r0, k0) \
  GLDS16(gB + (size_t)(r0) * K_DIM + (k0), ldsw + 16384 + (c) * 16384 + (r0) * 64)

#define STAGE6(d, k1)                                                         \
  STAGE_B(d, 0, k1); STAGE_B(d, 64, k1);                                      \
  STAGE_B(d, 128, k1); STAGE_B(d, 192, k1);                                   \
  STAGE_A(d, 0, k1); STAGE_A(d, 64, k1);

  // fragment read: row = base + fr (bases mult-16), desired chunk kq,
  // slot = kq ^ ((fr>>1)&3)  (base contributes 0 mod 4 to (row>>1)&3).
  const int sA = kq ^ ((fr >> 1) & 3);

  // v4i-unit base pointers; every fragment read is ds_read_b128 base+imm.
  const v4i* pA = (const v4i*)lds + (fr * 4 + sA);
  const v4i* pB = (const v4i*)(lds + 16384) + ((w * 64 + fr) * 4 + sA);

#define LDA_LO(dst, c)                                                        \
  {                                                                           \
    _Pragma("unroll") for (int mi = 0; mi < 4; ++mi)                          \
        dst[mi] = pA[((c) << 9) + (mi << 6)];                                 \
  }
#define LDA_HI(dst, c)                                                        \
  {                                                                           \
    _Pragma("unroll") for (int mi = 0; mi < 4; ++mi)                          \
        dst[mi] = pA[((c) << 9) + ((mi + 4) << 6)];                           \
  }
#define LDB4(dst, c)                                                          \
  {                                                                           \
    _Pragma("unroll") for (int ni = 0; ni < 4; ++ni)                          \
        dst[ni] = pB[((c) << 10) + (ni << 6)];                                \
  }

#define MFMA_BLK(MH, A_, B_)                                                  \
  __builtin_amdgcn_s_setprio(1);                                              \
  _Pragma("unroll") for (int ni = 0; ni < 4; ++ni)                            \
      _Pragma("unroll") for (int mi = 0; mi < 4; ++mi)                        \
          acc[(MH) * 4 + mi][ni] = __builtin_amdgcn_mfma_i32_16x16x64_i8(     \
              A_[mi], B_[ni], acc[(MH) * 4 + mi][ni], 0, 0, 0);               \
  __builtin_amdgcn_s_setprio(0);

  v4i acc[8][4];
#pragma unroll
  for (int i = 0; i < 8; ++i)
#pragma unroll
    for (int jj = 0; jj < 4; ++jj) acc[i][jj] = (v4i){0, 0, 0, 0};

  v4i a0[4], a1[4], b0[4];

  // One K-tile: stage next tile (6 GLDS), read A-hi fragments, two 16-MFMA
  // blocks, single vmcnt(0)+barrier, prefetch next tile's A-lo + B.
#define TILE(c, d, k1)                                                        \
  STAGE6(d, k1);                                                              \
  LDA_HI(a1, c);                                                              \
  MFMA_BLK(0, a0, b0);                                                        \
  MFMA_BLK(1, a1, b0);                                                        \
  VMCNT0();                                                                   \
  BARRIER();                                                                  \
  LDA_LO(a0, d);                                                              \
  LDB4(b0, d);

#define TILE_LAST(c)                                                          \
  LDA_HI(a1, c);                                                              \
  MFMA_BLK(0, a0, b0);                                                        \
  MFMA_BLK(1, a1, b0);

  // prologue: tile0 -> buf0; drain; load tile0's A-lo + B fragments.
  STAGE6(0, 0);
  VMCNT0();
  BARRIER();
  LDA_LO(a0, 0);
  LDB4(b0, 0);

  for (int tt = 0; tt < NTILES - 2; tt += 2) {  // tiles 0..61
    TILE(0, 1, (tt + 1) * BKB);
    TILE(1, 0, (tt + 2) * BKB);
  }
  TILE(0, 1, (NTILES - 1) * BKB);  // tile 62, stages tile 63
  TILE_LAST(1);                    // tile 63

  // epilogue: C/D layout col = lane&15, row = (lane>>4)*4 + reg
  const int orow0 = rowBase;
  const int ocol0 = colBase + w * 64;
  const int rsub = kq * 4;
#pragma unroll
  for (int mi = 0; mi < 8; ++mi) {
    const int r0 = orow0 + mi * 16 + rsub;  // multiple of 4 -> float4 load
    const float4 s4v = *reinterpret_cast<const float4*>(xs + r0);
    const float s4[4] = {s4v.x, s4v.y, s4v.z, s4v.w};
#pragma unroll
    for (int ni = 0; ni < 4; ++ni) {
      const int col = ocol0 + ni * 16 + fr;
      const float wf = wsc[col];
      const float bb = bias[col];
#pragma unroll
      for (int r = 0; r < 4; ++r)
        out[(size_t)(r0 + r) * N_DIM + col] =
            (float)acc[mi][ni][r] * s4[r] * wf + bb;
    }
  }
}

// ---------------------------------------------------------------------------
extern "C" void kernel_launch(void* const* d_in, const int* in_sizes, int n_in,
                              void* d_out, int out_size, void* d_ws,
                              size_t ws_size, hipStream_t stream) {
  const float* x = (const float*)d_in[0];
  const int* w32 = (const int*)d_in[1];
  const float* wscale = (const float*)d_in[2];
  const float* bias = (const float*)d_in[3];
  float* out = (float*)d_out;

  int8_t* xq = (int8_t*)d_ws;
  float* xs = (float*)((char*)d_ws + (size_t)M_DIM * K_DIM);
  int8_t* w8 = (int8_t*)((char*)d_ws + (size_t)M_DIM * K_DIM + M_DIM * 4);

  const int packBlocks = (N_DIM * K_DIM) / (256 * 16);  // 12288
  prep<<<M_DIM + packBlocks, 256, 0, stream>>>(x, xq, xs, w32, w8);
  gemm_i8<<<(M_DIM / BM) * (N_DIM / BN), 256, 0, stream>>>(xq, xs, w8, wscale,
                                                           bias, out);
}

// Round 17
// 495.767 us; speedup vs baseline: 1.1584x; 1.0739x over previous
//
#include <hip/hip_runtime.h>
#include <stdint.h>

#define M_DIM 8192
#define K_DIM 4096
#define N_DIM 12288

typedef int v4i __attribute__((ext_vector_type(4)));

#define GLDS16(g, l)                                                         \
  __builtin_amdgcn_global_load_lds(                                          \
      (const __attribute__((address_space(1))) void*)(g),                    \
      (__attribute__((address_space(3))) void*)(l), 16, 0, 0)

#define BARRIER() asm volatile("s_barrier" ::: "memory")
#define VMCNT0() asm volatile("s_waitcnt vmcnt(0)" ::: "memory")

// ---------------------------------------------------------------------------
// Fused prep: blocks [0, M) quantize x rows; blocks [M, M+12288) pack weights
// row-major int8 (proven path, unchanged).
// ---------------------------------------------------------------------------
__global__ __launch_bounds__(256) void prep(const float* __restrict__ x,
                                            int8_t* __restrict__ xq,
                                            float* __restrict__ xs,
                                            const int* __restrict__ w32,
                                            int8_t* __restrict__ w8) {
  const int t = threadIdx.x;
  if ((int)blockIdx.x < M_DIM) {
    const int row = blockIdx.x;
    const float* xr = x + (size_t)row * K_DIM;

    float4 v[4];
    float amax = 0.f;
#pragma unroll
    for (int i = 0; i < 4; ++i) {
      v[i] = reinterpret_cast<const float4*>(xr)[t * 4 + i];
      amax = fmaxf(amax, fmaxf(fmaxf(fabsf(v[i].x), fabsf(v[i].y)),
                               fmaxf(fabsf(v[i].z), fabsf(v[i].w))));
    }
#pragma unroll
    for (int off = 32; off > 0; off >>= 1)
      amax = fmaxf(amax, __shfl_xor(amax, off));

    __shared__ float smax[4];
    if ((t & 63) == 0) smax[t >> 6] = amax;
    __syncthreads();
    amax = fmaxf(fmaxf(smax[0], smax[1]), fmaxf(smax[2], smax[3]));

    const float scale = fmaxf(amax, 1e-8f) / 127.f;

    union {
      int8_t b[16];
      v4i v;
    } p;
    const float* pv = reinterpret_cast<const float*>(v);
#pragma unroll
    for (int i = 0; i < 16; ++i) {
      float r = rintf(pv[i] / scale);  // round-half-to-even == jnp.round
      r = fminf(127.f, fmaxf(-127.f, r));
      p.b[i] = (int8_t)(int)r;
    }
    reinterpret_cast<v4i*>(xq + (size_t)row * K_DIM)[t] = p.v;
    if (t == 0) xs[row] = scale;
  } else {
    const size_t i = (((size_t)blockIdx.x - M_DIM) * 256 + t) * 16;
    const int4* src = reinterpret_cast<const int4*>(w32 + i);
    union {
      int8_t b[16];
      v4i v;
    } p;
#pragma unroll
    for (int c = 0; c < 4; ++c) {
      int4 q = src[c];
      p.b[c * 4 + 0] = (int8_t)q.x;
      p.b[c * 4 + 1] = (int8_t)q.y;
      p.b[c * 4 + 2] = (int8_t)q.z;
      p.b[c * 4 + 3] = (int8_t)q.w;
    }
    *reinterpret_cast<v4i*>(w8 + i) = p.v;
  }
}

// ---------------------------------------------------------------------------
// int8 GEMM r17 = r13 (proven best: 385 us, MfmaUtil 51%, 0 conflicts) with
// s_setprio REMOVED (single-variable A/B; m190: setprio costs ~1.5% on
// lockstep non-phase-split GEMM structures -- exactly this one).
// 256x256 tile, BK=128B, 8 waves (2Mx4N), 16x16x64 MFMA, one vmcnt(0)+
// barrier per K-tile, XOR-swizzled global_load_lds staging, base+imm
// ds_read_b128 fragment reads, bijective 4Mx8N XCD windows.
// ---------------------------------------------------------------------------
#define BM 256
#define BN 256
#define BKB 128                 // K bytes per tile
#define NTILES (K_DIM / BKB)    // 32

__global__ __launch_bounds__(512, 2) void gemm_i8(
    const int8_t* __restrict__ xq, const float* __restrict__ xs,
    const int8_t* __restrict__ w8, const float* __restrict__ wsc,
    const float* __restrict__ bias, float* __restrict__ out) {
  // LDS map: A bufs at c*32768 (256 rows x 128B), B bufs at 65536 + c*32768.
  __shared__ __align__(16) int8_t lds[131072];

  const int t = threadIdx.x;
  const int lane = t & 63;
  const int w = t >> 6;      // wave 0..7
  const int wr = w >> 2;     // 0..1 -> 128-row block
  const int wc = w & 3;      // 0..3 -> 64-col block
  const int fr = lane & 15;
  const int kq = lane >> 4;  // 0..3
  const int l7 = lane & 7;

  // 2D XCD swizzle: XCD x owns M-tiles [4x,4x+4); 4M x 8N windows
  // (bijective: 8 xcd * 6 g * 32 j = 1536).
  const int bid = (int)blockIdx.x;
  const int xcd = bid & 7;
  const int q = bid >> 3;    // [0,192)
  const int g = q >> 5;      // [0,6)
  const int j = q & 31;
  const int rowBase = (xcd * 4 + (j >> 3)) * BM;
  const int colBase = (g * 8 + (j & 7)) * BN;

  // staging: thread t -> row srow = t>>3, lds 16B-slot t&7; inverse swizzle on
  // the GLOBAL source so lds(R,S) holds global chunk S ^ (R&7).
  const int srow = t >> 3;
  const int gslot = (t & 7) ^ (srow & 7);
  const int8_t* gA = xq + (size_t)(rowBase + srow) * K_DIM + gslot * 16;
  const int8_t* gB = w8 + (size_t)(colBase + srow) * K_DIM + gslot * 16;
  int8_t* ldsw = lds + w * 1024;  // wave-uniform dest base (HW adds lane*16)

#define STAGE_A(c, r0, k0) \
  GLDS16(gA + (size_t)(r0) * K_DIM + (k0), ldsw + (c) * 32768 + (r0) * 128)
#define STAGE_B(c, r0, k0) \
  GLDS16(gB + (size_t)(r0) * K_DIM + (k0), ldsw + 65536 + (c) * 32768 + (r0) * 128)

#define STAGE8(d, k1)                                                         \
  STAGE_B(d, 0, k1); STAGE_B(d, 64, k1);                                      \
  STAGE_B(d, 128, k1); STAGE_B(d, 192, k1);                                   \
  STAGE_A(d, 0, k1); STAGE_A(d, 64, k1);                                      \
  STAGE_A(d, 128, k1); STAGE_A(d, 192, k1);

  // fragment read slot: (ks*4 + kq) ^ (row&7); row&7 == l7 (bases mult-16).
  const int s0_ = kq ^ l7;        // ks=0
  const int s1_ = s0_ ^ 4;        // ks=1
  const int rA = wr * 128 + fr;   // + mh*64 + mi*16
  const int rB = wc * 64 + fr;    // + ni*16

  // Precomputed per-thread LDS base pointers; every fragment read is a single
  // ds_read_b128 with a 16-bit immediate (max imm 47104 < 65536).
  const v4i* pA0 = (const v4i*)lds + ((rA << 3) + s0_);
  const v4i* pA1 = (const v4i*)lds + ((rA << 3) + s1_);
  const v4i* pB0 = (const v4i*)(lds + 65536) + ((rB << 3) + s0_);
  const v4i* pB1 = (const v4i*)(lds + 65536) + ((rB << 3) + s1_);

#define LDA(dst, c, mh, ks)                                                   \
  {                                                                           \
    const v4i* _p = (ks) ? pA1 : pA0;                                         \
    dst[0] = _p[((c) << 11) + (((mh) * 64 + 0) << 3)];                        \
    dst[1] = _p[((c) << 11) + (((mh) * 64 + 16) << 3)];                       \
    dst[2] = _p[((c) << 11) + (((mh) * 64 + 32) << 3)];                       \
    dst[3] = _p[((c) << 11) + (((mh) * 64 + 48) << 3)];                       \
  }
#define LDB(dst, c, ks)                                                       \
  {                                                                           \
    const v4i* _p = (ks) ? pB1 : pB0;                                         \
    dst[0] = _p[((c) << 11) + (0 << 3)];                                      \
    dst[1] = _p[((c) << 11) + (16 << 3)];                                     \
    dst[2] = _p[((c) << 11) + (32 << 3)];                                     \
    dst[3] = _p[((c) << 11) + (48 << 3)];                                     \
  }

#define MFMA_BLK(MH, A_, B_)                                                  \
  _Pragma("unroll") for (int ni = 0; ni < 4; ++ni)                            \
      _Pragma("unroll") for (int mi = 0; mi < 4; ++mi)                        \
          acc[(MH) * 4 + mi][ni] = __builtin_amdgcn_mfma_i32_16x16x64_i8(     \
              A_[mi], B_[ni], acc[(MH) * 4 + mi][ni], 0, 0, 0);

  v4i acc[8][4];
#pragma unroll
  for (int i = 0; i < 8; ++i)
#pragma unroll
    for (int jj = 0; jj < 4; ++jj) acc[i][jj] = (v4i){0, 0, 0, 0};

  v4i a0[4], a1[4], b0[4], b1[4];

  // One K-tile: stage next tile at top, 4 software-pipelined MFMA blocks,
  // single vmcnt+barrier at end, then prefetch next tile's first fragments.
#define TILE(c, d, k1)                                                        \
  STAGE8(d, k1);                                                              \
  LDA(a1, c, 1, 0);                                                           \
  MFMA_BLK(0, a0, b0);                                                        \
  LDA(a0, c, 0, 1);                                                           \
  LDB(b1, c, 1);                                                              \
  MFMA_BLK(1, a1, b0);                                                        \
  LDA(a1, c, 1, 1);                                                           \
  MFMA_BLK(0, a0, b1);                                                        \
  MFMA_BLK(1, a1, b1);                                                        \
  VMCNT0();                                                                   \
  BARRIER();                                                                  \
  LDA(a0, d, 0, 0);                                                           \
  LDB(b0, d, 0);

#define TILE_LAST(c)                                                          \
  LDA(a1, c, 1, 0);                                                           \
  MFMA_BLK(0, a0, b0);                                                        \
  LDA(a0, c, 0, 1);                                                           \
  LDB(b1, c, 1);                                                              \
  MFMA_BLK(1, a1, b0);                                                        \
  LDA(a1, c, 1, 1);                                                           \
  MFMA_BLK(0, a0, b1);                                                        \
  MFMA_BLK(1, a1, b1);

  // prologue: tile0 -> buf0; drain; load tile0's first fragment sets.
  STAGE8(0, 0);
  VMCNT0();
  BARRIER();
  LDA(a0, 0, 0, 0);
  LDB(b0, 0, 0);

  for (int tt = 0; tt < NTILES - 2; tt += 2) {  // tiles 0..29
    TILE(0, 1, (tt + 1) * BKB);
    TILE(1, 0, (tt + 2) * BKB);
  }
  TILE(0, 1, (NTILES - 1) * BKB);  // tile 30, stages tile 31
  TILE_LAST(1);                    // tile 31

  // epilogue: C/D layout col = lane&15, row = (lane>>4)*4 + reg
  const int orow0 = rowBase + wr * 128;
  const int ocol0 = colBase + wc * 64;
  const int rsub = kq * 4;
#pragma unroll
  for (int mi8 = 0; mi8 < 8; ++mi8) {
    const int r0 = orow0 + mi8 * 16 + rsub;  // multiple of 4 -> float4 load
    const float4 s4v = *reinterpret_cast<const float4*>(xs + r0);
    const float s4[4] = {s4v.x, s4v.y, s4v.z, s4v.w};
#pragma unroll
    for (int ni = 0; ni < 4; ++ni) {
      const int col = ocol0 + ni * 16 + fr;
      const float wf = wsc[col];
      const float bb = bias[col];
#pragma unroll
      for (int r = 0; r < 4; ++r)
        out[(size_t)(r0 + r) * N_DIM + col] =
            (float)acc[mi8][ni][r] * s4[r] * wf + bb;
    }
  }
}

// ---------------------------------------------------------------------------
extern "C" void kernel_launch(void* const* d_in, const int* in_sizes, int n_in,
                              void* d_out, int out_size, void* d_ws,
                              size_t ws_size, hipStream_t stream) {
  const float* x = (const float*)d_in[0];
  const int* w32 = (const int*)d_in[1];
  const float* wscale = (const float*)d_in[2];
  const float* bias = (const float*)d_in[3];
  float* out = (float*)d_out;

  int8_t* xq = (int8_t*)d_ws;
  float* xs = (float*)((char*)d_ws + (size_t)M_DIM * K_DIM);
  int8_t* w8 = (int8_t*)((char*)d_ws + (size_t)M_DIM * K_DIM + M_DIM * 4);

  const int packBlocks = (N_DIM * K_DIM) / (256 * 16);  // 12288
  prep<<<M_DIM + packBlocks, 256, 0, stream>>>(x, xq, xs, w32, w8);
  gemm_i8<<<(M_DIM / BM) * (N_DIM / BN), 512, 0, stream>>>(xq, xs, w8, wscale,
                                                           bias, out);
}